// Round 4
// baseline (890.528 us; speedup 1.0000x reference)
//
#include <hip/hip_runtime.h>
#include <hip/hip_bf16.h>
#include <stdint.h>

// MLA forward: B=2,S=2048,H=2048,NH=16,D=128,LAT=512. Inputs are fp32 (R3-confirmed).
// R4: m97 global_load_lds GEMM staging; fused proj4 + UK|UV GEMMs; flash BN=32,
// launch_bounds(256,3), no P-barrier.
typedef __hip_bfloat16 bf16;
typedef __attribute__((ext_vector_type(8))) short s8v;   // 8 x bf16 (4 VGPRs)
typedef __attribute__((ext_vector_type(4))) float f4v;   // MFMA 16x16 accum

__device__ __forceinline__ void gld16(const bf16* g, bf16* l) {
  __builtin_amdgcn_global_load_lds(
      (__attribute__((address_space(1))) unsigned int*)g,
      (__attribute__((address_space(3))) unsigned int*)l, 16, 0, 0);
}

__device__ __forceinline__ f4v mfma16(s8v a, s8v b, f4v c) {
  return __builtin_amdgcn_mfma_f32_16x16x32_bf16(a, b, c, 0, 0, 0);
}

__device__ __forceinline__ unsigned short f2bfu(float f) {
  union { bf16 h; unsigned short u; } cv;
  cv.h = __float2bfloat16(f);
  return cv.u;
}

// ------------- dtype detect (kept for robustness; fp32 expected) -------------
__global__ void detect_dtype(const void* __restrict__ hs, int* __restrict__ flag) {
  if (threadIdx.x != 0) return;
  const unsigned short* u = (const unsigned short*)hs;
  int big = 0;
  for (int i = 0; i < 2048; i++) {
    unsigned short e = (u[i] >> 7) & 0xFF;
    if (e > 133) big++;
  }
  *flag = (big > 64) ? 1 : 0;  // 1 => buffers hold fp32
}

// ------------- hs convert: (fp32|bf16) -> bf16, 8 elems/thread -------------
__global__ void convert_hs(const void* __restrict__ in, bf16* __restrict__ out,
                           const int* __restrict__ flag, int n) {
  int i = (blockIdx.x * 256 + threadIdx.x) * 8;
  if (i >= n) return;
  if (*flag) {
    const float* f = (const float*)in;
    union { s8v v; unsigned short u[8]; } pk;
#pragma unroll
    for (int j = 0; j < 8; j++) pk.u[j] = f2bfu(f[i + j]);
    *(s8v*)(out + i) = pk.v;
  } else {
    *(s8v*)(out + i) = *(const s8v*)((const bf16*)in + i);
  }
}

// ------------- all-bias convert: 8 arrays in one launch -------------
__global__ void convert_bias_all(
    const void* b0, const void* b1, const void* b2, const void* b3,
    const void* b4, const void* b5, const void* b6, const void* b7,
    float* o0, float* o1, float* o2, float* o3,
    float* o4, float* o5, float* o6, float* o7,
    const int* __restrict__ flag) {
  const void* src; float* dst; int len;
  switch (blockIdx.y) {
    case 0: src = b0; dst = o0; len = 512;  break;
    case 1: src = b1; dst = o1; len = 512;  break;
    case 2: src = b2; dst = o2; len = 2048; break;
    case 3: src = b3; dst = o3; len = 2048; break;
    case 4: src = b4; dst = o4; len = 2048; break;
    case 5: src = b5; dst = o5; len = 128;  break;
    case 6: src = b6; dst = o6; len = 128;  break;
    default: src = b7; dst = o7; len = 2048; break;
  }
  int i = blockIdx.x * 256 + threadIdx.x;
  if (i >= len) return;
  dst[i] = (*flag) ? ((const float*)src)[i]
                   : __bfloat162float(((const bf16*)src)[i]);
}

// ------------- weight transpose: in (R x C, fp32|bf16) -> out (C x R, bf16) -------------
__global__ void transpose_any(const void* __restrict__ in, bf16* __restrict__ out,
                              int R, int C, const int* __restrict__ flag) {
  __shared__ float t[32][33];
  int tx = threadIdx.x & 31, ty = threadIdx.x >> 5;  // 256 thr: 32x8
  int c0 = blockIdx.x * 32, r0 = blockIdx.y * 32;
  bool f32 = (*flag != 0);
#pragma unroll
  for (int i = 0; i < 32; i += 8) {
    size_t src = (size_t)(r0 + ty + i) * C + c0 + tx;
    t[ty + i][tx] = f32 ? ((const float*)in)[src]
                        : __bfloat162float(((const bf16*)in)[src]);
  }
  __syncthreads();
#pragma unroll
  for (int i = 0; i < 32; i += 8)
    out[(size_t)(c0 + ty + i) * R + r0 + tx] = __float2bfloat16(t[tx][ty + i]);
}

// ---------------- rope (both k and q in one launch) ----------------
__global__ void rope_kernel(const bf16* __restrict__ inK, bf16* __restrict__ outK,
                            const bf16* __restrict__ inQ, bf16* __restrict__ outQ) {
  const bf16* in = (blockIdx.y == 0) ? inK : inQ;
  bf16* out = (blockIdx.y == 0) ? outK : outQ;
  int row = blockIdx.x;       // b*2048 + s
  int d = threadIdx.x;        // 0..63
  int pos = row & 2047;
  float x1 = __bfloat162float(in[(size_t)row * 128 + d]);
  float x2 = __bfloat162float(in[(size_t)row * 128 + 64 + d]);
  float inv = exp2f(-(float)d * (13.287712379549449f / 64.0f));  // 10000^(-d/64)
  float ang = (float)pos * inv;
  float sn = sinf(ang), cs = cosf(ang);
  out[(size_t)row * 128 + d]      = __float2bfloat16(x1 * cs - x2 * sn);
  out[(size_t)row * 128 + 64 + d] = __float2bfloat16(x1 * sn + x2 * cs);
}

// ---------------- GEMM: C(MxN) = A(MxK) @ Bt(NxK)^T + bias ----------------
// m97 structure: 128x128 tile, BK=32, 4 waves (2x2), global_load_lds w=16.
// MODE 0: plain bf16 out (C0, stride N).
// MODE 1: fused proj4 -> c_kv(512) | c_q(512) | krl(128) | qrl(128).
// MODE 2: fused UK|UV -> k_c (n<2048, stride 2048) | vT layout (n>=2048).
// MODE 3: external out C0: fp32 if *flag else bf16.
template <int MODE>
__global__ __launch_bounds__(256) void gemm_bt(
    const bf16* __restrict__ A, const bf16* __restrict__ Bt,
    const float* __restrict__ bias,
    void* __restrict__ C0, void* __restrict__ C1,
    void* __restrict__ C2, void* __restrict__ C3,
    int M, int N, int K, const int* __restrict__ flag) {
  __shared__ bf16 sA[128 * 32];
  __shared__ bf16 sB[128 * 32];
  const int tid = threadIdx.x, lane = tid & 63, wid = tid >> 6;
  const int l15 = lane & 15, l4 = lane >> 4;
  const int m0 = blockIdx.y * 128, n0 = blockIdx.x * 128;
  const int wm = (wid >> 1) * 64, wn = (wid & 1) * 64;
  f4v acc[4][4] = {};
  const bf16* gA = A + (size_t)m0 * K;
  const bf16* gB = Bt + (size_t)n0 * K;
  const int row = tid >> 2, col = (tid & 3) * 8;
  for (int k0 = 0; k0 < K; k0 += 32) {
    gld16(gA + (size_t)row * K + k0 + col,        sA + tid * 8);
    gld16(gA + (size_t)(row + 64) * K + k0 + col, sA + (tid + 256) * 8);
    gld16(gB + (size_t)row * K + k0 + col,        sB + tid * 8);
    gld16(gB + (size_t)(row + 64) * K + k0 + col, sB + (tid + 256) * 8);
    __syncthreads();
    s8v a[4], b[4];
#pragma unroll
    for (int i = 0; i < 4; i++) a[i] = *(const s8v*)(sA + (wm + i * 16 + l15) * 32 + l4 * 8);
#pragma unroll
    for (int j = 0; j < 4; j++) b[j] = *(const s8v*)(sB + (wn + j * 16 + l15) * 32 + l4 * 8);
#pragma unroll
    for (int i = 0; i < 4; i++)
#pragma unroll
      for (int j = 0; j < 4; j++) acc[i][j] = mfma16(a[i], b[j], acc[i][j]);
    __syncthreads();
  }
  // epilogue. C/D layout: row = l4*4+g, col = l15 (within 16x16 tile)
#pragma unroll
  for (int j = 0; j < 4; j++) {
    const int nb = n0 + wn + j * 16;      // 16-col tile base (uniform per j)
    const int n = nb + l15;
    const float bv = bias[n];
    if (MODE == 0 || MODE == 3) {
      bool f32o = (MODE == 3) && (*flag != 0);
#pragma unroll
      for (int i = 0; i < 4; i++) {
        size_t mb = m0 + wm + i * 16 + l4 * 4;
#pragma unroll
        for (int g = 0; g < 4; g++) {
          float val = acc[i][j][g] + bv;
          size_t idx = (mb + g) * (size_t)N + n;
          if (MODE == 3 && f32o) ((float*)C0)[idx] = val;
          else                   ((bf16*)C0)[idx] = __float2bfloat16(val);
        }
      }
    } else if (MODE == 1) {
      bf16* dst; int stride, nc;
      if (nb < 512)       { dst = (bf16*)C0; stride = 512; nc = n; }
      else if (nb < 1024) { dst = (bf16*)C1; stride = 512; nc = n - 512; }
      else if (nb < 1152) { dst = (bf16*)C2; stride = 128; nc = n - 1024; }
      else                { dst = (bf16*)C3; stride = 128; nc = n - 1152; }
#pragma unroll
      for (int i = 0; i < 4; i++) {
        size_t mb = m0 + wm + i * 16 + l4 * 4;
#pragma unroll
        for (int g = 0; g < 4; g++)
          dst[(mb + g) * (size_t)stride + nc] = __float2bfloat16(acc[i][j][g] + bv);
      }
    } else {  // MODE 2: UK (k_c) | UV (vT)
      if (nb < 2048) {
        bf16* dst = (bf16*)C0;
#pragma unroll
        for (int i = 0; i < 4; i++) {
          size_t mb = m0 + wm + i * 16 + l4 * 4;
#pragma unroll
          for (int g = 0; g < 4; g++)
            dst[(mb + g) * (size_t)2048 + n] = __float2bfloat16(acc[i][j][g] + bv);
        }
      } else {
        bf16* dst = (bf16*)C1;
        int nn = n - 2048, hh = nn >> 7, dd = nn & 127;
#pragma unroll
        for (int i = 0; i < 4; i++) {
          int m = m0 + wm + i * 16 + l4 * 4;
          int bb = m >> 11, ss = m & 2047;
          unsigned int lo = f2bfu(acc[i][j][0] + bv) | ((unsigned int)f2bfu(acc[i][j][1] + bv) << 16);
          unsigned int hi = f2bfu(acc[i][j][2] + bv) | ((unsigned int)f2bfu(acc[i][j][3] + bv) << 16);
          size_t dstoff = ((size_t)(bb * 16 + hh) * 128 + dd) * 2048 + ss;
          uint2 pk; pk.x = lo; pk.y = hi;
          *reinterpret_cast<uint2*>(dst + dstoff) = pk;
        }
      }
    }
  }
}

// ---------------- flash attention ----------------
// grid (S/128, B*NH), 256 thr (4 waves; wave owns 32 q-rows). BN=32 keys/iter.
// LDS: sK/sKr = [dchunk(16)][key(32)][8], sVT = [kch(4)][d(128)][8], sP/wave 2KB.
__global__ __launch_bounds__(256, 3) void flash_attn(
    const bf16* __restrict__ Qc, const bf16* __restrict__ Kc,
    const bf16* __restrict__ Qr, const bf16* __restrict__ Kr,
    const bf16* __restrict__ VT, const int* __restrict__ amask,
    bf16* __restrict__ ctx) {
  const int S = 2048, H = 2048, D = 128;
  __shared__ bf16 sK[16 * 32 * 8];
  __shared__ bf16 sKr[16 * 32 * 8];
  __shared__ bf16 sVT[4 * 128 * 8];
  __shared__ bf16 sP[4][4 * 32 * 8];  // per-wave P: [kchunk(4)][q(32)][8]

  const int tid = threadIdx.x, lane = tid & 63, wid = tid >> 6;
  const int l15 = lane & 15, l4 = lane >> 4;
  const int qt = blockIdx.x, bh = blockIdx.y;
  const int b = bh >> 4, h = bh & 15;
  const size_t bS = (size_t)b * S;
  const int q0 = qt * 128 + wid * 32;

  // Q fragments in registers (A-operand: m=l15, k=l4*8+j)
  s8v qcf[2][4], qrf[2][4];
#pragma unroll
  for (int r = 0; r < 2; r++) {
    size_t qrow = bS + q0 + r * 16 + l15;
    const bf16* pc = Qc + qrow * H + h * D + l4 * 8;
    const bf16* pr = Qr + qrow * D + l4 * 8;
#pragma unroll
    for (int t = 0; t < 4; t++) {
      qcf[r][t] = *(const s8v*)(pc + t * 32);
      qrf[r][t] = *(const s8v*)(pr + t * 32);
    }
  }

  f4v oacc[2][8] = {};
  float mrow[2][4], lrow[2][4];
#pragma unroll
  for (int r = 0; r < 2; r++)
#pragma unroll
    for (int g = 0; g < 4; g++) { mrow[r][g] = -1e30f; lrow[r][g] = 0.f; }

  const float scl = 0.08838834764831845f;  // 1/sqrt(128)

  for (int kv0 = 0; kv0 < S; kv0 += 32) {
#pragma unroll
    for (int p = 0; p < 2; p++) {
      int idx = tid + p * 256;
      int key = idx & 31, dch = idx >> 5;
      gld16(Kc + (bS + kv0 + key) * H + h * D + dch * 8, sK + idx * 8);
      gld16(Kr + (bS + kv0 + key) * D + dch * 8, sKr + idx * 8);
      int d = idx & 127, kch = idx >> 7;
      gld16(VT + ((size_t)bh * D + d) * S + kv0 + kch * 8, sVT + idx * 8);
    }
    __syncthreads();

    int mv[2];
#pragma unroll
    for (int c = 0; c < 2; c++) mv[c] = amask[bS + kv0 + c * 16 + l15];

    // S = Qc.Kc^T + Qr.Kr^T   (B-frag: n=c*16+l15, kchunk=t*4+l4)
    f4v sc[2][2] = {};
#pragma unroll
    for (int c = 0; c < 2; c++) {
#pragma unroll
      for (int t = 0; t < 4; t++) {
        s8v kf = *(const s8v*)(sK + ((t * 4 + l4) * 32 + c * 16 + l15) * 8);
        sc[0][c] = mfma16(qcf[0][t], kf, sc[0][c]);
        sc[1][c] = mfma16(qcf[1][t], kf, sc[1][c]);
      }
#pragma unroll
      for (int t = 0; t < 4; t++) {
        s8v kf = *(const s8v*)(sKr + ((t * 4 + l4) * 32 + c * 16 + l15) * 8);
        sc[0][c] = mfma16(qrf[0][t], kf, sc[0][c]);
        sc[1][c] = mfma16(qrf[1][t], kf, sc[1][c]);
      }
    }

    // online softmax (fp32); score row = l4*4+g, col = c*16+l15
#pragma unroll
    for (int r = 0; r < 2; r++) {
#pragma unroll
      for (int g = 0; g < 4; g++) {
        float v[2];
#pragma unroll
        for (int c = 0; c < 2; c++) {
          float x = sc[r][c][g] * scl;
          v[c] = (mv[c] == 0) ? -1e30f : x;
        }
        float mx = fmaxf(v[0], v[1]);
#pragma unroll
        for (int off = 8; off; off >>= 1) mx = fmaxf(mx, __shfl_xor(mx, off, 64));
        float mn = fmaxf(mrow[r][g], mx);
        float alpha = __expf(mrow[r][g] - mn);
        mrow[r][g] = mn;
        float ps = 0.f;
        float pv[2];
#pragma unroll
        for (int c = 0; c < 2; c++) { pv[c] = __expf(v[c] - mn); ps += pv[c]; }
#pragma unroll
        for (int off = 8; off; off >>= 1) ps += __shfl_xor(ps, off, 64);
        lrow[r][g] = lrow[r][g] * alpha + ps;
#pragma unroll
        for (int c = 0; c < 8; c++) oacc[r][c][g] *= alpha;
        int qr_ = r * 16 + l4 * 4 + g;
#pragma unroll
        for (int c = 0; c < 2; c++) {
          int kch = 2 * c + (l15 >> 3);
          sP[wid][(kch * 32 + qr_) * 8 + (l15 & 7)] = __float2bfloat16(pv[c]);
        }
      }
    }
    // same-wave ds_write -> ds_read ordering (no block barrier needed)
    asm volatile("s_waitcnt lgkmcnt(0)" ::: "memory");

    // O += P @ V  (P A-frag: m=l15(q), kchunk=l4; V B-frag: n=c*16+l15(d), kchunk=l4)
    {
      s8v pf0 = *(const s8v*)(sP[wid] + (l4 * 32 + 0 + l15) * 8);
      s8v pf1 = *(const s8v*)(sP[wid] + (l4 * 32 + 16 + l15) * 8);
#pragma unroll
      for (int c = 0; c < 8; c++) {
        s8v vf = *(const s8v*)(sVT + (l4 * 128 + c * 16 + l15) * 8);
        oacc[0][c] = mfma16(pf0, vf, oacc[0][c]);
        oacc[1][c] = mfma16(pf1, vf, oacc[1][c]);
      }
    }
    __syncthreads();
  }

  // normalize + store ctx (B,S,H)
#pragma unroll
  for (int r = 0; r < 2; r++) {
#pragma unroll
    for (int c = 0; c < 8; c++) {
#pragma unroll
      for (int g = 0; g < 4; g++) {
        int qrow = q0 + r * 16 + l4 * 4 + g;
        float val = oacc[r][c][g] / lrow[r][g];
        ctx[(bS + qrow) * H + h * D + c * 16 + l15] = __float2bfloat16(val);
      }
    }
  }
}

// ---------------- launch ----------------
extern "C" void kernel_launch(void* const* d_in, const int* in_sizes, int n_in,
                              void* d_out, int out_size, void* d_ws, size_t ws_size,
                              hipStream_t stream) {
  const void* hs    = d_in[0];
  const int*  amask = (const int*)d_in[1];
  const void* W_DKV = d_in[2];  const void* b_DKV = d_in[3];
  const void* W_DQ  = d_in[4];  const void* b_DQ  = d_in[5];
  const void* W_UK  = d_in[6];  const void* b_UK  = d_in[7];
  const void* W_UV  = d_in[8];  const void* b_UV  = d_in[9];
  const void* W_UQ  = d_in[10]; const void* b_UQ  = d_in[11];
  const void* W_KR  = d_in[12]; const void* b_KR  = d_in[13];
  const void* W_QR  = d_in[14]; const void* b_QR  = d_in[15];
  const void* W_O   = d_in[16]; const void* b_O   = d_in[17];

  char* wsb = (char*)d_ws;
  size_t off = 0;
  auto allocB = [&](size_t bytes) {
    void* p = wsb + off; off = (off + bytes + 255) & ~(size_t)255; return p;
  };
  int*   flag   = (int*)allocB(4);
  // concat bias block for proj4 (order matters: dkv|dq|kr|qr)
  float* fb_dkv = (float*)allocB(512 * 4);
  float* fb_dq  = (float*)allocB(512 * 4);
  float* fb_kr  = (float*)allocB(128 * 4);
  float* fb_qr  = (float*)allocB(128 * 4);
  // concat bias block for UK|UV
  float* fb_uk  = (float*)allocB(2048 * 4);
  float* fb_uv  = (float*)allocB(2048 * 4);
  float* fb_uq  = (float*)allocB(2048 * 4);
  float* fb_o   = (float*)allocB(2048 * 4);
  bf16* hsb    = (bf16*)allocB((size_t)4096 * 2048 * 2);
  // concat weight block for proj4 (dkv|dq|kr|qr), each N x K (K=2048)
  bf16* wt_dkv = (bf16*)allocB((size_t)512 * 2048 * 2);
  bf16* wt_dq  = (bf16*)allocB((size_t)512 * 2048 * 2);
  bf16* wt_kr  = (bf16*)allocB((size_t)128 * 2048 * 2);
  bf16* wt_qr  = (bf16*)allocB((size_t)128 * 2048 * 2);
  // concat weight block for UK|UV, each 2048 x 512
  bf16* wt_uk  = (bf16*)allocB((size_t)2048 * 512 * 2);
  bf16* wt_uv  = (bf16*)allocB((size_t)2048 * 512 * 2);
  bf16* wt_uq  = (bf16*)allocB((size_t)2048 * 512 * 2);
  bf16* wt_o   = (bf16*)allocB((size_t)2048 * 2048 * 2);
  bf16* c_kv   = (bf16*)allocB((size_t)4096 * 512 * 2);
  bf16* c_q    = (bf16*)allocB((size_t)4096 * 512 * 2);
  bf16* krl    = (bf16*)allocB((size_t)4096 * 128 * 2);
  bf16* qrl    = (bf16*)allocB((size_t)4096 * 128 * 2);
  bf16* k_r    = (bf16*)allocB((size_t)4096 * 128 * 2);
  bf16* q_r    = (bf16*)allocB((size_t)4096 * 128 * 2);
  bf16* k_c    = (bf16*)allocB((size_t)4096 * 2048 * 2);
  bf16* q_c    = (bf16*)allocB((size_t)4096 * 2048 * 2);
  bf16* vT     = (bf16*)allocB((size_t)4096 * 2048 * 2);
  bf16* ctx    = (bf16*)allocB((size_t)4096 * 2048 * 2);

  detect_dtype<<<1, 64, 0, stream>>>(hs, flag);

  // ingest
  convert_hs<<<4096, 256, 0, stream>>>(hs, hsb, flag, 4096 * 2048);
  convert_bias_all<<<dim3(8, 8), 256, 0, stream>>>(
      b_DKV, b_DQ, b_UK, b_UV, b_UQ, b_KR, b_QR, b_O,
      fb_dkv, fb_dq, fb_uk, fb_uv, fb_uq, fb_kr, fb_qr, fb_o, flag);
  transpose_any<<<dim3(16, 64), 256, 0, stream>>>(W_DKV, wt_dkv, 2048, 512, flag);
  transpose_any<<<dim3(16, 64), 256, 0, stream>>>(W_DQ,  wt_dq,  2048, 512, flag);
  transpose_any<<<dim3(4, 64), 256, 0, stream>>>(W_KR,  wt_kr,  2048, 128, flag);
  transpose_any<<<dim3(4, 64), 256, 0, stream>>>(W_QR,  wt_qr,  2048, 128, flag);
  transpose_any<<<dim3(64, 16), 256, 0, stream>>>(W_UK,  wt_uk,  512, 2048, flag);
  transpose_any<<<dim3(64, 16), 256, 0, stream>>>(W_UV,  wt_uv,  512, 2048, flag);
  transpose_any<<<dim3(64, 16), 256, 0, stream>>>(W_UQ,  wt_uq,  512, 2048, flag);
  transpose_any<<<dim3(64, 64), 256, 0, stream>>>(W_O,  wt_o, 2048, 2048, flag);

  // fused projections: N = 512|512|128|128 = 1280, K = 2048
  gemm_bt<1><<<dim3(10, 32), 256, 0, stream>>>(
      hsb, wt_dkv, fb_dkv, c_kv, c_q, krl, qrl, 4096, 1280, 2048, flag);
  rope_kernel<<<dim3(4096, 2), 64, 0, stream>>>(krl, k_r, qrl, q_r);

  // fused UK|UV: N = 2048|2048 = 4096, K = 512
  gemm_bt<2><<<dim3(32, 32), 256, 0, stream>>>(
      c_kv, wt_uk, fb_uk, k_c, vT, nullptr, nullptr, 4096, 4096, 512, flag);
  // UQ
  gemm_bt<0><<<dim3(16, 32), 256, 0, stream>>>(
      c_q, wt_uq, fb_uq, q_c, nullptr, nullptr, nullptr, 4096, 2048, 512, flag);

  // attention
  flash_attn<<<dim3(16, 32), 256, 0, stream>>>(q_c, k_c, q_r, k_r, vT, amask, ctx);

  // output projection (dtype-flagged external write)
  gemm_bt<3><<<dim3(16, 32), 256, 0, stream>>>(
      ctx, wt_o, fb_o, d_out, nullptr, nullptr, nullptr, 4096, 2048, 2048, flag);
}

// Round 5
// 603.533 us; speedup vs baseline: 1.4755x; 1.4755x over previous
//
#include <hip/hip_runtime.h>
#include <hip/hip_bf16.h>
#include <stdint.h>

// MLA forward: B=2,S=2048,H=2048,NH=16,D=128,LAT=512. Inputs fp32 (R3-confirmed).
// R5: flash back to BN=64, launch_bounds(256,2) -- R4's (256,3) caused scratch
// spills (WRITE_SIZE 680MB). GEMM side unchanged from R4 (523->352us win).
typedef __hip_bfloat16 bf16;
typedef __attribute__((ext_vector_type(8))) short s8v;   // 8 x bf16 (4 VGPRs)
typedef __attribute__((ext_vector_type(4))) float f4v;   // MFMA 16x16 accum

__device__ __forceinline__ void gld16(const bf16* g, bf16* l) {
  __builtin_amdgcn_global_load_lds(
      (__attribute__((address_space(1))) unsigned int*)g,
      (__attribute__((address_space(3))) unsigned int*)l, 16, 0, 0);
}

__device__ __forceinline__ f4v mfma16(s8v a, s8v b, f4v c) {
  return __builtin_amdgcn_mfma_f32_16x16x32_bf16(a, b, c, 0, 0, 0);
}

__device__ __forceinline__ unsigned short f2bfu(float f) {
  union { bf16 h; unsigned short u; } cv;
  cv.h = __float2bfloat16(f);
  return cv.u;
}

// ------------- dtype detect (kept for robustness; fp32 expected) -------------
__global__ void detect_dtype(const void* __restrict__ hs, int* __restrict__ flag) {
  if (threadIdx.x != 0) return;
  const unsigned short* u = (const unsigned short*)hs;
  int big = 0;
  for (int i = 0; i < 2048; i++) {
    unsigned short e = (u[i] >> 7) & 0xFF;
    if (e > 133) big++;
  }
  *flag = (big > 64) ? 1 : 0;  // 1 => buffers hold fp32
}

// ------------- hs convert: (fp32|bf16) -> bf16, 8 elems/thread -------------
__global__ void convert_hs(const void* __restrict__ in, bf16* __restrict__ out,
                           const int* __restrict__ flag, int n) {
  int i = (blockIdx.x * 256 + threadIdx.x) * 8;
  if (i >= n) return;
  if (*flag) {
    const float* f = (const float*)in;
    union { s8v v; unsigned short u[8]; } pk;
#pragma unroll
    for (int j = 0; j < 8; j++) pk.u[j] = f2bfu(f[i + j]);
    *(s8v*)(out + i) = pk.v;
  } else {
    *(s8v*)(out + i) = *(const s8v*)((const bf16*)in + i);
  }
}

// ------------- all-bias convert: 8 arrays in one launch -------------
__global__ void convert_bias_all(
    const void* b0, const void* b1, const void* b2, const void* b3,
    const void* b4, const void* b5, const void* b6, const void* b7,
    float* o0, float* o1, float* o2, float* o3,
    float* o4, float* o5, float* o6, float* o7,
    const int* __restrict__ flag) {
  const void* src; float* dst; int len;
  switch (blockIdx.y) {
    case 0: src = b0; dst = o0; len = 512;  break;
    case 1: src = b1; dst = o1; len = 512;  break;
    case 2: src = b2; dst = o2; len = 2048; break;
    case 3: src = b3; dst = o3; len = 2048; break;
    case 4: src = b4; dst = o4; len = 2048; break;
    case 5: src = b5; dst = o5; len = 128;  break;
    case 6: src = b6; dst = o6; len = 128;  break;
    default: src = b7; dst = o7; len = 2048; break;
  }
  int i = blockIdx.x * 256 + threadIdx.x;
  if (i >= len) return;
  dst[i] = (*flag) ? ((const float*)src)[i]
                   : __bfloat162float(((const bf16*)src)[i]);
}

// ------------- weight transpose: in (R x C, fp32|bf16) -> out (C x R, bf16) -------------
__global__ void transpose_any(const void* __restrict__ in, bf16* __restrict__ out,
                              int R, int C, const int* __restrict__ flag) {
  __shared__ float t[32][33];
  int tx = threadIdx.x & 31, ty = threadIdx.x >> 5;  // 256 thr: 32x8
  int c0 = blockIdx.x * 32, r0 = blockIdx.y * 32;
  bool f32 = (*flag != 0);
#pragma unroll
  for (int i = 0; i < 32; i += 8) {
    size_t src = (size_t)(r0 + ty + i) * C + c0 + tx;
    t[ty + i][tx] = f32 ? ((const float*)in)[src]
                        : __bfloat162float(((const bf16*)in)[src]);
  }
  __syncthreads();
#pragma unroll
  for (int i = 0; i < 32; i += 8)
    out[(size_t)(c0 + ty + i) * R + r0 + tx] = __float2bfloat16(t[tx][ty + i]);
}

// ---------------- rope (both k and q in one launch) ----------------
__global__ void rope_kernel(const bf16* __restrict__ inK, bf16* __restrict__ outK,
                            const bf16* __restrict__ inQ, bf16* __restrict__ outQ) {
  const bf16* in = (blockIdx.y == 0) ? inK : inQ;
  bf16* out = (blockIdx.y == 0) ? outK : outQ;
  int row = blockIdx.x;       // b*2048 + s
  int d = threadIdx.x;        // 0..63
  int pos = row & 2047;
  float x1 = __bfloat162float(in[(size_t)row * 128 + d]);
  float x2 = __bfloat162float(in[(size_t)row * 128 + 64 + d]);
  float inv = exp2f(-(float)d * (13.287712379549449f / 64.0f));  // 10000^(-d/64)
  float ang = (float)pos * inv;
  float sn = sinf(ang), cs = cosf(ang);
  out[(size_t)row * 128 + d]      = __float2bfloat16(x1 * cs - x2 * sn);
  out[(size_t)row * 128 + 64 + d] = __float2bfloat16(x1 * sn + x2 * cs);
}

// ---------------- GEMM: C(MxN) = A(MxK) @ Bt(NxK)^T + bias ----------------
// m97 structure: 128x128 tile, BK=32, 4 waves (2x2), global_load_lds w=16.
// MODE 0: plain bf16 out (C0, stride N).
// MODE 1: fused proj4 -> c_kv(512) | c_q(512) | krl(128) | qrl(128).
// MODE 2: fused UK|UV -> k_c (n<2048, stride 2048) | vT layout (n>=2048).
// MODE 3: external out C0: fp32 if *flag else bf16.
template <int MODE>
__global__ __launch_bounds__(256) void gemm_bt(
    const bf16* __restrict__ A, const bf16* __restrict__ Bt,
    const float* __restrict__ bias,
    void* __restrict__ C0, void* __restrict__ C1,
    void* __restrict__ C2, void* __restrict__ C3,
    int M, int N, int K, const int* __restrict__ flag) {
  __shared__ bf16 sA[128 * 32];
  __shared__ bf16 sB[128 * 32];
  const int tid = threadIdx.x, lane = tid & 63, wid = tid >> 6;
  const int l15 = lane & 15, l4 = lane >> 4;
  const int m0 = blockIdx.y * 128, n0 = blockIdx.x * 128;
  const int wm = (wid >> 1) * 64, wn = (wid & 1) * 64;
  f4v acc[4][4] = {};
  const bf16* gA = A + (size_t)m0 * K;
  const bf16* gB = Bt + (size_t)n0 * K;
  const int row = tid >> 2, col = (tid & 3) * 8;
  for (int k0 = 0; k0 < K; k0 += 32) {
    gld16(gA + (size_t)row * K + k0 + col,        sA + tid * 8);
    gld16(gA + (size_t)(row + 64) * K + k0 + col, sA + (tid + 256) * 8);
    gld16(gB + (size_t)row * K + k0 + col,        sB + tid * 8);
    gld16(gB + (size_t)(row + 64) * K + k0 + col, sB + (tid + 256) * 8);
    __syncthreads();
    s8v a[4], b[4];
#pragma unroll
    for (int i = 0; i < 4; i++) a[i] = *(const s8v*)(sA + (wm + i * 16 + l15) * 32 + l4 * 8);
#pragma unroll
    for (int j = 0; j < 4; j++) b[j] = *(const s8v*)(sB + (wn + j * 16 + l15) * 32 + l4 * 8);
#pragma unroll
    for (int i = 0; i < 4; i++)
#pragma unroll
      for (int j = 0; j < 4; j++) acc[i][j] = mfma16(a[i], b[j], acc[i][j]);
    __syncthreads();
  }
  // epilogue. C/D layout: row = l4*4+g, col = l15 (within 16x16 tile)
#pragma unroll
  for (int j = 0; j < 4; j++) {
    const int nb = n0 + wn + j * 16;      // 16-col tile base (uniform per j)
    const int n = nb + l15;
    const float bv = bias[n];
    if (MODE == 0 || MODE == 3) {
      bool f32o = (MODE == 3) && (*flag != 0);
#pragma unroll
      for (int i = 0; i < 4; i++) {
        size_t mb = m0 + wm + i * 16 + l4 * 4;
#pragma unroll
        for (int g = 0; g < 4; g++) {
          float val = acc[i][j][g] + bv;
          size_t idx = (mb + g) * (size_t)N + n;
          if (MODE == 3 && f32o) ((float*)C0)[idx] = val;
          else                   ((bf16*)C0)[idx] = __float2bfloat16(val);
        }
      }
    } else if (MODE == 1) {
      bf16* dst; int stride, nc;
      if (nb < 512)       { dst = (bf16*)C0; stride = 512; nc = n; }
      else if (nb < 1024) { dst = (bf16*)C1; stride = 512; nc = n - 512; }
      else if (nb < 1152) { dst = (bf16*)C2; stride = 128; nc = n - 1024; }
      else                { dst = (bf16*)C3; stride = 128; nc = n - 1152; }
#pragma unroll
      for (int i = 0; i < 4; i++) {
        size_t mb = m0 + wm + i * 16 + l4 * 4;
#pragma unroll
        for (int g = 0; g < 4; g++)
          dst[(mb + g) * (size_t)stride + nc] = __float2bfloat16(acc[i][j][g] + bv);
      }
    } else {  // MODE 2: UK (k_c) | UV (vT)
      if (nb < 2048) {
        bf16* dst = (bf16*)C0;
#pragma unroll
        for (int i = 0; i < 4; i++) {
          size_t mb = m0 + wm + i * 16 + l4 * 4;
#pragma unroll
          for (int g = 0; g < 4; g++)
            dst[(mb + g) * (size_t)2048 + n] = __float2bfloat16(acc[i][j][g] + bv);
        }
      } else {
        bf16* dst = (bf16*)C1;
        int nn = n - 2048, hh = nn >> 7, dd = nn & 127;
#pragma unroll
        for (int i = 0; i < 4; i++) {
          int m = m0 + wm + i * 16 + l4 * 4;
          int bb = m >> 11, ss = m & 2047;
          unsigned int lo = f2bfu(acc[i][j][0] + bv) | ((unsigned int)f2bfu(acc[i][j][1] + bv) << 16);
          unsigned int hi = f2bfu(acc[i][j][2] + bv) | ((unsigned int)f2bfu(acc[i][j][3] + bv) << 16);
          size_t dstoff = ((size_t)(bb * 16 + hh) * 128 + dd) * 2048 + ss;
          uint2 pk; pk.x = lo; pk.y = hi;
          *reinterpret_cast<uint2*>(dst + dstoff) = pk;
        }
      }
    }
  }
}

// ---------------- flash attention ----------------
// grid (S/128, B*NH), 256 thr (4 waves; wave owns 32 q-rows). BN=64 keys/iter.
// LDS: sK/sKr = [dchunk(16)][key(64)][8], sVT = [kch(8)][d(128)][8], sP/wave 4KB.
// launch_bounds(256,2): register floor ~200/wave -> 2 waves/SIMD; (256,3) spills.
__global__ __launch_bounds__(256, 2) void flash_attn(
    const bf16* __restrict__ Qc, const bf16* __restrict__ Kc,
    const bf16* __restrict__ Qr, const bf16* __restrict__ Kr,
    const bf16* __restrict__ VT, const int* __restrict__ amask,
    bf16* __restrict__ ctx) {
  const int S = 2048, H = 2048, D = 128;
  __shared__ bf16 sK[16 * 64 * 8];
  __shared__ bf16 sKr[16 * 64 * 8];
  __shared__ bf16 sVT[8 * 128 * 8];
  __shared__ bf16 sP[4][8 * 32 * 8];  // per-wave P: [kchunk(8)][q(32)][8]

  const int tid = threadIdx.x, lane = tid & 63, wid = tid >> 6;
  const int l15 = lane & 15, l4 = lane >> 4;
  const int qt = blockIdx.x, bh = blockIdx.y;
  const int b = bh >> 4, h = bh & 15;
  const size_t bS = (size_t)b * S;
  const int q0 = qt * 128 + wid * 32;

  // Q fragments in registers (A-operand: m=l15, k=l4*8+j)
  s8v qcf[2][4], qrf[2][4];
#pragma unroll
  for (int r = 0; r < 2; r++) {
    size_t qrow = bS + q0 + r * 16 + l15;
    const bf16* pc = Qc + qrow * H + h * D + l4 * 8;
    const bf16* pr = Qr + qrow * D + l4 * 8;
#pragma unroll
    for (int t = 0; t < 4; t++) {
      qcf[r][t] = *(const s8v*)(pc + t * 32);
      qrf[r][t] = *(const s8v*)(pr + t * 32);
    }
  }

  f4v oacc[2][8] = {};
  float mrow[2][4], lrow[2][4];
#pragma unroll
  for (int r = 0; r < 2; r++)
#pragma unroll
    for (int g = 0; g < 4; g++) { mrow[r][g] = -1e30f; lrow[r][g] = 0.f; }

  const float scl = 0.08838834764831845f;  // 1/sqrt(128)

  for (int kv0 = 0; kv0 < S; kv0 += 64) {
#pragma unroll
    for (int p = 0; p < 4; p++) {
      int idx = tid + p * 256;
      int key = idx & 63, dch = idx >> 6;
      gld16(Kc + (bS + kv0 + key) * H + h * D + dch * 8, sK + idx * 8);
      gld16(Kr + (bS + kv0 + key) * D + dch * 8, sKr + idx * 8);
      int d = idx & 127, kch = idx >> 7;
      gld16(VT + ((size_t)bh * D + d) * S + kv0 + kch * 8, sVT + idx * 8);
    }
    __syncthreads();

    int mv[4];
#pragma unroll
    for (int c = 0; c < 4; c++) mv[c] = amask[bS + kv0 + c * 16 + l15];

    // S = Qc.Kc^T + Qr.Kr^T   (B-frag: n=c*16+l15, kchunk=t*4+l4)
    f4v sc[2][4] = {};
#pragma unroll
    for (int c = 0; c < 4; c++) {
#pragma unroll
      for (int t = 0; t < 4; t++) {
        s8v kf = *(const s8v*)(sK + ((t * 4 + l4) * 64 + c * 16 + l15) * 8);
        sc[0][c] = mfma16(qcf[0][t], kf, sc[0][c]);
        sc[1][c] = mfma16(qcf[1][t], kf, sc[1][c]);
      }
#pragma unroll
      for (int t = 0; t < 4; t++) {
        s8v kf = *(const s8v*)(sKr + ((t * 4 + l4) * 64 + c * 16 + l15) * 8);
        sc[0][c] = mfma16(qrf[0][t], kf, sc[0][c]);
        sc[1][c] = mfma16(qrf[1][t], kf, sc[1][c]);
      }
    }

    // online softmax (fp32); score row = l4*4+g, col = c*16+l15
#pragma unroll
    for (int r = 0; r < 2; r++) {
#pragma unroll
      for (int g = 0; g < 4; g++) {
        float v[4];
#pragma unroll
        for (int c = 0; c < 4; c++) {
          float x = sc[r][c][g] * scl;
          v[c] = (mv[c] == 0) ? -1e30f : x;
        }
        float mx = fmaxf(fmaxf(v[0], v[1]), fmaxf(v[2], v[3]));
#pragma unroll
        for (int off = 8; off; off >>= 1) mx = fmaxf(mx, __shfl_xor(mx, off, 64));
        float mn = fmaxf(mrow[r][g], mx);
        float alpha = __expf(mrow[r][g] - mn);
        mrow[r][g] = mn;
        float ps = 0.f;
        float pv[4];
#pragma unroll
        for (int c = 0; c < 4; c++) { pv[c] = __expf(v[c] - mn); ps += pv[c]; }
#pragma unroll
        for (int off = 8; off; off >>= 1) ps += __shfl_xor(ps, off, 64);
        lrow[r][g] = lrow[r][g] * alpha + ps;
#pragma unroll
        for (int c = 0; c < 8; c++) oacc[r][c][g] *= alpha;
        int qr_ = r * 16 + l4 * 4 + g;
#pragma unroll
        for (int c = 0; c < 4; c++) {
          int kch = 2 * c + (l15 >> 3);
          sP[wid][(kch * 32 + qr_) * 8 + (l15 & 7)] = __float2bfloat16(pv[c]);
        }
      }
    }
    // same-wave ds_write -> ds_read ordering (no block barrier needed)
    asm volatile("s_waitcnt lgkmcnt(0)" ::: "memory");

    // O += P @ V  (P A-frag: m=l15(q), kchunk=t*4+l4; V B-frag: n=c*16+l15(d))
#pragma unroll
    for (int t = 0; t < 2; t++) {
      s8v pf0 = *(const s8v*)(sP[wid] + ((t * 4 + l4) * 32 + 0 + l15) * 8);
      s8v pf1 = *(const s8v*)(sP[wid] + ((t * 4 + l4) * 32 + 16 + l15) * 8);
#pragma unroll
      for (int c = 0; c < 8; c++) {
        s8v vf = *(const s8v*)(sVT + ((t * 4 + l4) * 128 + c * 16 + l15) * 8);
        oacc[0][c] = mfma16(pf0, vf, oacc[0][c]);
        oacc[1][c] = mfma16(pf1, vf, oacc[1][c]);
      }
    }
    __syncthreads();
  }

  // normalize + store ctx (B,S,H)
#pragma unroll
  for (int r = 0; r < 2; r++) {
    float inv_l[4];
#pragma unroll
    for (int g = 0; g < 4; g++) inv_l[g] = 1.0f / lrow[r][g];
#pragma unroll
    for (int c = 0; c < 8; c++) {
#pragma unroll
      for (int g = 0; g < 4; g++) {
        int qrow = q0 + r * 16 + l4 * 4 + g;
        float val = oacc[r][c][g] * inv_l[g];
        ctx[(bS + qrow) * H + h * D + c * 16 + l15] = __float2bfloat16(val);
      }
    }
  }
}

// ---------------- launch ----------------
extern "C" void kernel_launch(void* const* d_in, const int* in_sizes, int n_in,
                              void* d_out, int out_size, void* d_ws, size_t ws_size,
                              hipStream_t stream) {
  const void* hs    = d_in[0];
  const int*  amask = (const int*)d_in[1];
  const void* W_DKV = d_in[2];  const void* b_DKV = d_in[3];
  const void* W_DQ  = d_in[4];  const void* b_DQ  = d_in[5];
  const void* W_UK  = d_in[6];  const void* b_UK  = d_in[7];
  const void* W_UV  = d_in[8];  const void* b_UV  = d_in[9];
  const void* W_UQ  = d_in[10]; const void* b_UQ  = d_in[11];
  const void* W_KR  = d_in[12]; const void* b_KR  = d_in[13];
  const void* W_QR  = d_in[14]; const void* b_QR  = d_in[15];
  const void* W_O   = d_in[16]; const void* b_O   = d_in[17];

  char* wsb = (char*)d_ws;
  size_t off = 0;
  auto allocB = [&](size_t bytes) {
    void* p = wsb + off; off = (off + bytes + 255) & ~(size_t)255; return p;
  };
  int*   flag   = (int*)allocB(4);
  // concat bias block for proj4 (order matters: dkv|dq|kr|qr)
  float* fb_dkv = (float*)allocB(512 * 4);
  float* fb_dq  = (float*)allocB(512 * 4);
  float* fb_kr  = (float*)allocB(128 * 4);
  float* fb_qr  = (float*)allocB(128 * 4);
  // concat bias block for UK|UV
  float* fb_uk  = (float*)allocB(2048 * 4);
  float* fb_uv  = (float*)allocB(2048 * 4);
  float* fb_uq  = (float*)allocB(2048 * 4);
  float* fb_o   = (float*)allocB(2048 * 4);
  bf16* hsb    = (bf16*)allocB((size_t)4096 * 2048 * 2);
  // concat weight block for proj4 (dkv|dq|kr|qr), each N x K (K=2048)
  bf16* wt_dkv = (bf16*)allocB((size_t)512 * 2048 * 2);
  bf16* wt_dq  = (bf16*)allocB((size_t)512 * 2048 * 2);
  bf16* wt_kr  = (bf16*)allocB((size_t)128 * 2048 * 2);
  bf16* wt_qr  = (bf16*)allocB((size_t)128 * 2048 * 2);
  // concat weight block for UK|UV, each 2048 x 512
  bf16* wt_uk  = (bf16*)allocB((size_t)2048 * 512 * 2);
  bf16* wt_uv  = (bf16*)allocB((size_t)2048 * 512 * 2);
  bf16* wt_uq  = (bf16*)allocB((size_t)2048 * 512 * 2);
  bf16* wt_o   = (bf16*)allocB((size_t)2048 * 2048 * 2);
  bf16* c_kv   = (bf16*)allocB((size_t)4096 * 512 * 2);
  bf16* c_q    = (bf16*)allocB((size_t)4096 * 512 * 2);
  bf16* krl    = (bf16*)allocB((size_t)4096 * 128 * 2);
  bf16* qrl    = (bf16*)allocB((size_t)4096 * 128 * 2);
  bf16* k_r    = (bf16*)allocB((size_t)4096 * 128 * 2);
  bf16* q_r    = (bf16*)allocB((size_t)4096 * 128 * 2);
  bf16* k_c    = (bf16*)allocB((size_t)4096 * 2048 * 2);
  bf16* q_c    = (bf16*)allocB((size_t)4096 * 2048 * 2);
  bf16* vT     = (bf16*)allocB((size_t)4096 * 2048 * 2);
  bf16* ctx    = (bf16*)allocB((size_t)4096 * 2048 * 2);

  detect_dtype<<<1, 64, 0, stream>>>(hs, flag);

  // ingest
  convert_hs<<<4096, 256, 0, stream>>>(hs, hsb, flag, 4096 * 2048);
  convert_bias_all<<<dim3(8, 8), 256, 0, stream>>>(
      b_DKV, b_DQ, b_UK, b_UV, b_UQ, b_KR, b_QR, b_O,
      fb_dkv, fb_dq, fb_uk, fb_uv, fb_uq, fb_kr, fb_qr, fb_o, flag);
  transpose_any<<<dim3(16, 64), 256, 0, stream>>>(W_DKV, wt_dkv, 2048, 512, flag);
  transpose_any<<<dim3(16, 64), 256, 0, stream>>>(W_DQ,  wt_dq,  2048, 512, flag);
  transpose_any<<<dim3(4, 64), 256, 0, stream>>>(W_KR,  wt_kr,  2048, 128, flag);
  transpose_any<<<dim3(4, 64), 256, 0, stream>>>(W_QR,  wt_qr,  2048, 128, flag);
  transpose_any<<<dim3(64, 16), 256, 0, stream>>>(W_UK,  wt_uk,  512, 2048, flag);
  transpose_any<<<dim3(64, 16), 256, 0, stream>>>(W_UV,  wt_uv,  512, 2048, flag);
  transpose_any<<<dim3(64, 16), 256, 0, stream>>>(W_UQ,  wt_uq,  512, 2048, flag);
  transpose_any<<<dim3(64, 64), 256, 0, stream>>>(W_O,  wt_o, 2048, 2048, flag);

  // fused projections: N = 512|512|128|128 = 1280, K = 2048
  gemm_bt<1><<<dim3(10, 32), 256, 0, stream>>>(
      hsb, wt_dkv, fb_dkv, c_kv, c_q, krl, qrl, 4096, 1280, 2048, flag);
  rope_kernel<<<dim3(4096, 2), 64, 0, stream>>>(krl, k_r, qrl, q_r);

  // fused UK|UV: N = 2048|2048 = 4096, K = 512
  gemm_bt<2><<<dim3(32, 32), 256, 0, stream>>>(
      c_kv, wt_uk, fb_uk, k_c, vT, nullptr, nullptr, 4096, 4096, 512, flag);
  // UQ
  gemm_bt<0><<<dim3(16, 32), 256, 0, stream>>>(
      c_q, wt_uq, fb_uq, q_c, nullptr, nullptr, nullptr, 4096, 2048, 512, flag);

  // attention
  flash_attn<<<dim3(16, 32), 256, 0, stream>>>(q_c, k_c, q_r, k_r, vT, amask, ctx);

  // output projection (dtype-flagged external write)
  gemm_bt<3><<<dim3(16, 32), 256, 0, stream>>>(
      ctx, wt_o, fb_o, d_out, nullptr, nullptr, nullptr, 4096, 2048, 2048, flag);
}